// Round 3
// baseline (489.436 us; speedup 1.0000x reference)
//
#include <hip/hip_runtime.h>

typedef __bf16 bf16_t;
typedef __bf16 bf16x8 __attribute__((ext_vector_type(8)));
typedef __bf16 bf16x4v __attribute__((ext_vector_type(4)));
typedef float f32x4 __attribute__((ext_vector_type(4)));

#define GLDS16(g, l)                                                            \
  __builtin_amdgcn_global_load_lds((const __attribute__((address_space(1))) void*)(g), \
                                   (__attribute__((address_space(3))) void*)(l), 16, 0, 0)

// ================= fused prep: transposes + weight cvt/permute + counter zero =================
// block ranges: [0,5000) f2 T, [5000,6256) f3 T, [6256,6576) f4 T, [6576,6656) f5 T,
//               [6656,7680) W1 permute, [7680,8704) W2 cvt, [8704,10496) heads concat,
//               [10496] zero split-K counters
__global__ __launch_bounds__(256) void prep_all(const float* __restrict__ f2,
                                                const float* __restrict__ f3,
                                                const float* __restrict__ f4,
                                                const float* __restrict__ f5,
                                                const float* __restrict__ W1,
                                                const float* __restrict__ W2,
                                                const float* __restrict__ Wc,
                                                const float* __restrict__ bc,
                                                const float* __restrict__ Wr,
                                                const float* __restrict__ br,
                                                bf16_t* __restrict__ FT2,
                                                bf16_t* __restrict__ FT3,
                                                bf16_t* __restrict__ FT4,
                                                bf16_t* __restrict__ FT5,
                                                bf16_t* __restrict__ W1p,
                                                bf16_t* __restrict__ W2b,
                                                bf16_t* __restrict__ Wcb,
                                                float* __restrict__ bcat,
                                                int* __restrict__ cnt) {
  __shared__ __align__(16) char smraw[25344];
  const int bid = blockIdx.x;
  const int t = threadIdx.x;

  if (bid < 6656) {
    // ---- NCHW fp32 -> NHWC bf16 transpose, 64px x 64ch tile ----
    float* tile = (float*)smraw;   // 64*65 floats
    const float* src; bf16_t* dst; int P, rel, ptiles;
    if (bid < 5000)      { src = f2; dst = FT2; P = 40000; rel = bid;        ptiles = 625; }
    else if (bid < 6256) { src = f3; dst = FT3; P = 10000; rel = bid - 5000; ptiles = 157; }
    else if (bid < 6576) { src = f4; dst = FT4; P = 2500;  rel = bid - 6256; ptiles = 40; }
    else                 { src = f5; dst = FT5; P = 625;   rel = bid - 6576; ptiles = 10; }
    const int pt = rel % ptiles;
    const int cb = (rel / ptiles) & 3;
    const int b = rel / (ptiles * 4);
    const int p0 = pt * 64, c0 = cb * 64;
    const float* s = src + (size_t)(b * 256 + c0) * P;
#pragma unroll
    for (int it = 0; it < 16; ++it) {
      const int ch = it * 4 + (t >> 6);
      const int px = t & 63;
      float v = 0.0f;
      if (p0 + px < P) v = s[(size_t)ch * P + p0 + px];
      tile[ch * 65 + px] = v;
    }
    __syncthreads();
    bf16_t* d = dst + ((size_t)b * P + p0) * 256 + c0;
#pragma unroll
    for (int it = 0; it < 4; ++it) {
      const int px = it * 16 + (t >> 4);
      const int ch4 = (t & 15) * 4;
      if (p0 + px < P) {
        union { bf16_t bb[4]; uint2 u; } pk;
#pragma unroll
        for (int k2 = 0; k2 < 4; k2++) pk.bb[k2] = (bf16_t)tile[(ch4 + k2) * 65 + px];
        *(uint2*)&d[(size_t)px * 256 + ch4] = pk.u;
      }
    }
  } else if (bid < 7680) {
    // ---- W1 row: fp32 -> bf16 with K permuted c*49+bin -> bin*256+c ----
    bf16_t* pw = (bf16_t*)smraw;   // 49*258 bf16
    const int row = bid - 6656;
    const float* src = W1 + (size_t)row * 12544;
    for (int it = 0; it < 49; ++it) {
      const int j = it * 256 + t;
      const int c = j / 49;
      const int bin = j - c * 49;
      pw[bin * 258 + c] = (bf16_t)src[j];
    }
    __syncthreads();
    bf16_t* dst = W1p + (size_t)row * 12544;
    for (int j4 = t; j4 < 3136; j4 += 256) {
      const int bin = j4 >> 6;
      const int c = (j4 & 63) * 4;
      union { bf16_t bb[4]; uint2 u; } pk;
#pragma unroll
      for (int k2 = 0; k2 < 4; k2++) pk.bb[k2] = pw[bin * 258 + c + k2];
      ((uint2*)dst)[j4] = pk.u;
    }
  } else if (bid < 8704) {
    // ---- W2 fp32 -> bf16 ----
    const int i = (bid - 7680) * 256 + t;   // < 262144 float4s
    float4 v = ((const float4*)W2)[i];
    union { bf16_t b[4]; uint2 u; } p;
    p.b[0] = (bf16_t)v.x; p.b[1] = (bf16_t)v.y; p.b[2] = (bf16_t)v.z; p.b[3] = (bf16_t)v.w;
    ((uint2*)W2b)[i] = p.u;
  } else if (bid < 10496) {
    // ---- heads concat ----
    const int i = (bid - 8704) * 256 + t;   // over 448*1024
    const int row = i >> 10, col = i & 1023;
    float v = 0.0f;
    if (row < 81) v = Wc[row * 1024 + col];
    else if (row < 401) v = Wr[(row - 81) * 1024 + col];
    Wcb[i] = (bf16_t)v;
    if (i < 448) bcat[i] = (i < 81) ? bc[i] : ((i < 401) ? br[i - 81] : 0.0f);
  } else {
    if (t < 64) cnt[t] = 0;
  }
}

// ---------------- ROI align on NHWC bf16; A[n][bin*256 + c] ----------------
__global__ __launch_bounds__(256) void roi_align_nhwc(const bf16_t* __restrict__ fb2,
                                                      const bf16_t* __restrict__ fb3,
                                                      const bf16_t* __restrict__ fb4,
                                                      const bf16_t* __restrict__ fb5,
                                                      const float* __restrict__ rois,
                                                      bf16_t* __restrict__ A) {
  const int n = blockIdx.x;
  const int t = threadIdx.x;
  const int b = n >> 9;
  const float4 box = ((const float4*)rois)[n];
  const float w = box.z - box.x, h = box.w - box.y;
  const int lv = (int)floorf(4.0f + log2f(sqrtf(w * h) / 224.0f + 1e-6f));
  bf16_t* Ar = A + (size_t)n * 12544;

  if (lv < 2 || lv > 5) {
    uint2 z; z.x = 0; z.y = 0;
    for (int j = t; j < 3136; j += 256) ((uint2*)Ar)[j] = z;
    return;
  }

  const bf16_t* F; int H, W; float scale;
  if (lv == 2)      { F = fb2; H = 200; W = 200; scale = 0.25f; }
  else if (lv == 3) { F = fb3; H = 100; W = 100; scale = 0.125f; }
  else if (lv == 4) { F = fb4; H = 50;  W = 50;  scale = 0.0625f; }
  else              { F = fb5; H = 25;  W = 25;  scale = 0.03125f; }
  F += (size_t)b * H * W * 256;

  __shared__ int   s_x0[14], s_xb[14], s_y0w[14], s_ybw[14];
  __shared__ float s_wx0[14], s_wx1[14], s_wy0[14], s_wy1[14];

  const float x1s = box.x * scale, y1s = box.y * scale;
  const float x2s = box.z * scale, y2s = box.w * scale;
  const float rw = fmaxf(x2s - x1s, 1.0f), rh = fmaxf(y2s - y1s, 1.0f);
  const float bwx = rw * (1.0f / 7.0f), bwy = rh * (1.0f / 7.0f);

  if (t < 14) {
    const int i2 = t >> 1, j = t & 1;
    const float off = (float)i2 + ((float)j + 0.5f) * 0.5f;
    float x = x1s + off * bwx;
    float vx = (x > -1.0f && x < (float)W) ? 1.0f : 0.0f;
    x = fminf(fmaxf(x, 0.0f), (float)(W - 1));
    float x0f = floorf(x);
    int x0 = (int)x0f;
    s_x0[t] = x0; s_xb[t] = min(x0 + 1, W - 1);
    float lx = x - x0f;
    s_wx0[t] = (1.0f - lx) * vx; s_wx1[t] = lx * vx;
    float y = y1s + off * bwy;
    float vy = (y > -1.0f && y < (float)H) ? 1.0f : 0.0f;
    y = fminf(fmaxf(y, 0.0f), (float)(H - 1));
    float y0f = floorf(y);
    int y0 = (int)y0f;
    s_y0w[t] = y0 * W; s_ybw[t] = min(y0 + 1, H - 1) * W;
    float ly = y - y0f;
    s_wy0[t] = (1.0f - ly) * vy; s_wy1[t] = ly * vy;
  }
  __syncthreads();

  const int wv = t >> 6, l = t & 63;
  const int c4 = l * 4;
  for (int bin = wv; bin < 49; bin += 4) {
    const int by = bin / 7, bx = bin - by * 7;
    float a0 = 0, a1 = 0, a2 = 0, a3 = 0;
#pragma unroll
    for (int sa = 0; sa < 2; sa++) {
      const int my = 2 * by + sa;
      const int y0w = s_y0w[my], ybw = s_ybw[my];
      const float wy0 = s_wy0[my], wy1 = s_wy1[my];
#pragma unroll
      for (int sb = 0; sb < 2; sb++) {
        const int mx = 2 * bx + sb;
        const int x0 = s_x0[mx], xb = s_xb[mx];
        const float w00 = wy0 * s_wx0[mx], w01 = wy0 * s_wx1[mx];
        const float w10 = wy1 * s_wx0[mx], w11 = wy1 * s_wx1[mx];
        bf16x4v v00 = *(const bf16x4v*)&F[(size_t)(y0w + x0) * 256 + c4];
        bf16x4v v01 = *(const bf16x4v*)&F[(size_t)(y0w + xb) * 256 + c4];
        bf16x4v v10 = *(const bf16x4v*)&F[(size_t)(ybw + x0) * 256 + c4];
        bf16x4v v11 = *(const bf16x4v*)&F[(size_t)(ybw + xb) * 256 + c4];
        a0 += w00 * (float)v00[0] + w01 * (float)v01[0] + w10 * (float)v10[0] + w11 * (float)v11[0];
        a1 += w00 * (float)v00[1] + w01 * (float)v01[1] + w10 * (float)v10[1] + w11 * (float)v11[1];
        a2 += w00 * (float)v00[2] + w01 * (float)v01[2] + w10 * (float)v10[2] + w11 * (float)v11[2];
        a3 += w00 * (float)v00[3] + w01 * (float)v01[3] + w10 * (float)v10[3] + w11 * (float)v11[3];
      }
    }
    union { bf16_t bb[4]; uint2 u; } pk;
    pk.bb[0] = (bf16_t)(a0 * 0.25f);
    pk.bb[1] = (bf16_t)(a1 * 0.25f);
    pk.bb[2] = (bf16_t)(a2 * 0.25f);
    pk.bb[3] = (bf16_t)(a3 * 0.25f);
    *(uint2*)&Ar[bin * 256 + c4] = pk.u;
  }
}

// ------- fc1: 128x128 tile, GLDS w/ swizzle, split-K=8, fused last-block reduce -------
// LDS chunk swizzle: physical 16B slot s at row r holds logical chunk s ^ ((r>>1)&3).
__global__ __launch_bounds__(256, 2) void gemm1_splitk(const bf16_t* __restrict__ A,
                                                       const bf16_t* __restrict__ B,
                                                       const float* __restrict__ bias,
                                                       float* __restrict__ Cp,
                                                       bf16_t* __restrict__ X,
                                                       int* __restrict__ cnt) {
  __shared__ __align__(16) bf16_t As[128 * 32];
  __shared__ __align__(16) bf16_t Bs[128 * 32];
  const int t = threadIdx.x;
  const int w = t >> 6, l = t & 63;
  const int bm = blockIdx.x * 128, bn = blockIdx.y * 128;
  const int bz = blockIdx.z;
  const int K = 12544;
  const int k0 = bz * 1568;
  const int row1 = t >> 2;
  const int kc = ((t & 3) ^ ((t >> 3) & 3)) * 8;   // swizzled source chunk
  const bf16_t* gA1 = A + (size_t)(bm + row1) * K + k0 + kc;
  const bf16_t* gA2 = gA1 + (size_t)64 * K;
  const bf16_t* gB1 = B + (size_t)(bn + row1) * K + k0 + kc;
  const bf16_t* gB2 = gB1 + (size_t)64 * K;
  bf16_t* lA1 = As + w * 512;
  bf16_t* lA2 = As + 2048 + w * 512;
  bf16_t* lB1 = Bs + w * 512;
  bf16_t* lB2 = Bs + 2048 + w * 512;
  const int wm = (w >> 1) * 64, wn = (w & 1) * 64;
  const int rA = l & 15;
  const int kqs = (((l >> 4) ^ ((rA >> 1) & 3))) * 8;  // swizzled read chunk (row-uniform)
  f32x4 acc[4][4] = {};

  for (int kk = 0; kk < 49; ++kk) {
    GLDS16(gA1, lA1); GLDS16(gA2, lA2);
    GLDS16(gB1, lB1); GLDS16(gB2, lB2);
    gA1 += 32; gA2 += 32; gB1 += 32; gB2 += 32;
    __syncthreads();
    bf16x8 a[4], b[4];
#pragma unroll
    for (int i = 0; i < 4; i++) {
      a[i] = *(const bf16x8*)&As[(wm + i * 16 + rA) * 32 + kqs];
      b[i] = *(const bf16x8*)&Bs[(wn + i * 16 + rA) * 32 + kqs];
    }
#pragma unroll
    for (int i = 0; i < 4; i++)
#pragma unroll
      for (int j = 0; j < 4; j++)
        acc[i][j] = __builtin_amdgcn_mfma_f32_16x16x32_bf16(a[i], b[j], acc[i][j], 0, 0, 0);
    __syncthreads();
  }

  const int q = l >> 4, cc = l & 15;
  float* Co = Cp + ((size_t)bz << 20);
#pragma unroll
  for (int i = 0; i < 4; i++)
#pragma unroll
    for (int j = 0; j < 4; j++) {
      const int col = bn + wn + j * 16 + cc;
      const int r0 = bm + wm + i * 16 + q * 4;
#pragma unroll
      for (int r = 0; r < 4; r++)
        Co[(size_t)(r0 + r) * 1024 + col] = acc[i][j][r];
    }

  // last block for this (x,y) tile reduces all 8 partials
  __threadfence();
  __shared__ int s_last;
  if (t == 0) {
    int old = atomicAdd(&cnt[blockIdx.y * 8 + blockIdx.x], 1);
    s_last = (old == 7) ? 1 : 0;
  }
  __syncthreads();
  if (!s_last) return;
  __threadfence();

#pragma unroll
  for (int i = 0; i < 4; i++)
#pragma unroll
    for (int j = 0; j < 4; j++) {
      const int col = bn + wn + j * 16 + cc;
      const int r0 = bm + wm + i * 16 + q * 4;
      const float bv = bias[col];
#pragma unroll
      for (int r = 0; r < 4; r++) {
        float v = acc[i][j][r];
        const size_t off = (size_t)(r0 + r) * 1024 + col;
        for (int z2 = 0; z2 < 8; z2++)
          if (z2 != bz) v += Cp[((size_t)z2 << 20) + off];
        v = fmaxf(v + bv, 0.0f);
        X[off] = (bf16_t)v;
      }
    }
}

// ---------------- GEMM (64x64 tile, swizzled LDS): C = epi(A x B^T + bias) ----------------
template <int MODE>
__global__ __launch_bounds__(256) void gemm_bt(const bf16_t* __restrict__ A,
                                               const bf16_t* __restrict__ B,
                                               const float* __restrict__ bias,
                                               void* __restrict__ out,
                                               int M, int N, int K) {
  __shared__ __align__(16) bf16_t As[64 * 32];
  __shared__ __align__(16) bf16_t Bs[64 * 32];
  const int t = threadIdx.x;
  const int wv = t >> 6, l = t & 63;
  const int bm = blockIdx.x * 64, bn = blockIdx.y * 64;
  const int wm = (wv >> 1) * 32, wn = (wv & 1) * 32;

  const int srow = t >> 2;
  const int skc = (t & 3) * 8;                               // global chunk (contiguous)
  const int sst = ((t & 3) ^ ((t >> 3) & 3)) * 8;            // swizzled LDS store slot
  const bf16_t* ga = A + (size_t)(bm + srow) * K + skc;
  const bf16_t* gb = B + (size_t)(bn + srow) * K + skc;

  uint4 ra = *(const uint4*)ga;
  uint4 rb = *(const uint4*)gb;
  f32x4 acc[2][2] = {};

  const int nIter = K >> 5;
  const int rA = l & 15;
  const int kqs = (((l >> 4) ^ ((rA >> 1) & 3))) * 8;
  for (int i = 0; i < nIter; ++i) {
    ga += 32; gb += 32;
    *(uint4*)&As[srow * 32 + sst] = ra;
    *(uint4*)&Bs[srow * 32 + sst] = rb;
    __syncthreads();
    if (i + 1 < nIter) { ra = *(const uint4*)ga; rb = *(const uint4*)gb; }
    bf16x8 a0 = *(const bf16x8*)&As[(wm + rA) * 32 + kqs];
    bf16x8 a1 = *(const bf16x8*)&As[(wm + 16 + rA) * 32 + kqs];
    bf16x8 b0 = *(const bf16x8*)&Bs[(wn + rA) * 32 + kqs];
    bf16x8 b1 = *(const bf16x8*)&Bs[(wn + 16 + rA) * 32 + kqs];
    acc[0][0] = __builtin_amdgcn_mfma_f32_16x16x32_bf16(a0, b0, acc[0][0], 0, 0, 0);
    acc[0][1] = __builtin_amdgcn_mfma_f32_16x16x32_bf16(a0, b1, acc[0][1], 0, 0, 0);
    acc[1][0] = __builtin_amdgcn_mfma_f32_16x16x32_bf16(a1, b0, acc[1][0], 0, 0, 0);
    acc[1][1] = __builtin_amdgcn_mfma_f32_16x16x32_bf16(a1, b1, acc[1][1], 0, 0, 0);
    __syncthreads();
  }

  const int q = l >> 4;
  const int cc = l & 15;
#pragma unroll
  for (int i2 = 0; i2 < 2; i2++) {
#pragma unroll
    for (int j2 = 0; j2 < 2; j2++) {
      const int col = bn + wn + j2 * 16 + cc;
      const int row0 = bm + wm + i2 * 16 + q * 4;
      const float bv = bias[col];
#pragma unroll
      for (int r = 0; r < 4; r++) {
        float v = acc[i2][j2][r] + bv;
        const int row = row0 + r;
        if (MODE == 0) {
          v = fmaxf(v, 0.0f);
          ((bf16_t*)out)[(size_t)row * N + col] = (bf16_t)v;
        } else {
          if (col < 81)       ((float*)out)[(size_t)row * 81 + col] = v;
          else if (col < 401) ((float*)out)[82944 + (size_t)row * 320 + (col - 81)] = v;
        }
      }
    }
  }
}

extern "C" void kernel_launch(void* const* d_in, const int* in_sizes, int n_in,
                              void* d_out, int out_size, void* d_ws, size_t ws_size,
                              hipStream_t stream) {
  const float* f2   = (const float*)d_in[0];
  const float* f3   = (const float*)d_in[1];
  const float* f4   = (const float*)d_in[2];
  const float* f5   = (const float*)d_in[3];
  const float* rois = (const float*)d_in[4];
  const float* W1   = (const float*)d_in[5];
  const float* b1   = (const float*)d_in[6];
  const float* W2   = (const float*)d_in[7];
  const float* b2   = (const float*)d_in[8];
  const float* Wc   = (const float*)d_in[9];
  const float* bc   = (const float*)d_in[10];
  const float* Wr   = (const float*)d_in[11];
  const float* br   = (const float*)d_in[12];

  char* ws = (char*)d_ws;
  bf16_t* Ab   = (bf16_t*)(ws);                 // 1024x12544 bf16
  bf16_t* W1b  = (bf16_t*)(ws + 25690112);      // 1024x12544 bf16 (K-permuted)
  bf16_t* X1b  = (bf16_t*)(ws + 51380224);      // 1024x1024 bf16
  bf16_t* W2b  = (bf16_t*)(ws + 53477376);      // 1024x1024 bf16
  bf16_t* X2b  = (bf16_t*)(ws + 55574528);      // 1024x1024 bf16
  bf16_t* Wcb  = (bf16_t*)(ws + 57671680);      // 448x1024 bf16
  float*  bcat = (float*)(ws + 58589184);       // 448 fp32
  int*    cnt  = (int*)(ws + 58590976);         // 64 ints
  bf16_t* FT   = (bf16_t*)(ws + 58591232);      // NHWC feats bf16 (54.4 MB)
  float*  Cp   = (float*)(ws + 58591232);       // fc1 split-K partials (aliases FT)
  bf16_t* FT2 = FT;
  bf16_t* FT3 = FT + 20480000;
  bf16_t* FT4 = FT + 25600000;
  bf16_t* FT5 = FT + 26880000;

  prep_all<<<10497, 256, 0, stream>>>(f2, f3, f4, f5, W1, W2, Wc, bc, Wr, br,
                                      FT2, FT3, FT4, FT5, W1b, W2b, Wcb, bcat, cnt);
  roi_align_nhwc<<<1024, 256, 0, stream>>>(FT2, FT3, FT4, FT5, rois, Ab);
  gemm1_splitk<<<dim3(8, 8, 8), 256, 0, stream>>>(Ab, W1b, b1, Cp, X1b, cnt);
  gemm_bt<0><<<dim3(16, 16), 256, 0, stream>>>(X1b, W2b, b2, (void*)X2b, 1024, 1024, 1024);
  gemm_bt<1><<<dim3(16, 7), 256, 0, stream>>>(X2b, Wcb, bcat, d_out, 1024, 448, 1024);
}

// Round 4
// 327.017 us; speedup vs baseline: 1.4967x; 1.4967x over previous
//
#include <hip/hip_runtime.h>

typedef __bf16 bf16_t;
typedef __bf16 bf16x8 __attribute__((ext_vector_type(8)));
typedef __bf16 bf16x4v __attribute__((ext_vector_type(4)));
typedef float f32x4 __attribute__((ext_vector_type(4)));

#define GLDS16(g, l)                                                            \
  __builtin_amdgcn_global_load_lds((const __attribute__((address_space(1))) void*)(g), \
                                   (__attribute__((address_space(3))) void*)(l), 16, 0, 0)

// ================= fused prep: transposes + weight cvt/permute =================
// block ranges: [0,5000) f2 T, [5000,6256) f3 T, [6256,6576) f4 T, [6576,6656) f5 T,
//               [6656,7680) W1 permute, [7680,8704) W2 cvt, [8704,10496) heads concat
__global__ __launch_bounds__(256) void prep_all(const float* __restrict__ f2,
                                                const float* __restrict__ f3,
                                                const float* __restrict__ f4,
                                                const float* __restrict__ f5,
                                                const float* __restrict__ W1,
                                                const float* __restrict__ W2,
                                                const float* __restrict__ Wc,
                                                const float* __restrict__ bc,
                                                const float* __restrict__ Wr,
                                                const float* __restrict__ br,
                                                bf16_t* __restrict__ FT2,
                                                bf16_t* __restrict__ FT3,
                                                bf16_t* __restrict__ FT4,
                                                bf16_t* __restrict__ FT5,
                                                bf16_t* __restrict__ W1p,
                                                bf16_t* __restrict__ W2b,
                                                bf16_t* __restrict__ Wcb,
                                                float* __restrict__ bcat) {
  __shared__ __align__(16) char smraw[25344];
  const int bid = blockIdx.x;
  const int t = threadIdx.x;

  if (bid < 6656) {
    // ---- NCHW fp32 -> NHWC bf16 transpose, 64px x 64ch tile ----
    float* tile = (float*)smraw;   // 64*65 floats
    const float* src; bf16_t* dst; int P, rel, ptiles;
    if (bid < 5000)      { src = f2; dst = FT2; P = 40000; rel = bid;        ptiles = 625; }
    else if (bid < 6256) { src = f3; dst = FT3; P = 10000; rel = bid - 5000; ptiles = 157; }
    else if (bid < 6576) { src = f4; dst = FT4; P = 2500;  rel = bid - 6256; ptiles = 40; }
    else                 { src = f5; dst = FT5; P = 625;   rel = bid - 6576; ptiles = 10; }
    const int pt = rel % ptiles;
    const int cb = (rel / ptiles) & 3;
    const int b = rel / (ptiles * 4);
    const int p0 = pt * 64, c0 = cb * 64;
    const float* s = src + (size_t)(b * 256 + c0) * P;
#pragma unroll
    for (int it = 0; it < 16; ++it) {
      const int ch = it * 4 + (t >> 6);
      const int px = t & 63;
      float v = 0.0f;
      if (p0 + px < P) v = s[(size_t)ch * P + p0 + px];
      tile[ch * 65 + px] = v;
    }
    __syncthreads();
    bf16_t* d = dst + ((size_t)b * P + p0) * 256 + c0;
#pragma unroll
    for (int it = 0; it < 4; ++it) {
      const int px = it * 16 + (t >> 4);
      const int ch4 = (t & 15) * 4;
      if (p0 + px < P) {
        union { bf16_t bb[4]; uint2 u; } pk;
#pragma unroll
        for (int k2 = 0; k2 < 4; k2++) pk.bb[k2] = (bf16_t)tile[(ch4 + k2) * 65 + px];
        *(uint2*)&d[(size_t)px * 256 + ch4] = pk.u;
      }
    }
  } else if (bid < 7680) {
    // ---- W1 row: fp32 -> bf16 with K permuted c*49+bin -> bin*256+c ----
    bf16_t* pw = (bf16_t*)smraw;   // 49*258 bf16
    const int row = bid - 6656;
    const float* src = W1 + (size_t)row * 12544;
    for (int it = 0; it < 49; ++it) {
      const int j = it * 256 + t;
      const int c = j / 49;
      const int bin = j - c * 49;
      pw[bin * 258 + c] = (bf16_t)src[j];
    }
    __syncthreads();
    bf16_t* dst = W1p + (size_t)row * 12544;
    for (int j4 = t; j4 < 3136; j4 += 256) {
      const int bin = j4 >> 6;
      const int c = (j4 & 63) * 4;
      union { bf16_t bb[4]; uint2 u; } pk;
#pragma unroll
      for (int k2 = 0; k2 < 4; k2++) pk.bb[k2] = pw[bin * 258 + c + k2];
      ((uint2*)dst)[j4] = pk.u;
    }
  } else if (bid < 8704) {
    // ---- W2 fp32 -> bf16 ----
    const int i = (bid - 7680) * 256 + t;   // < 262144 float4s
    float4 v = ((const float4*)W2)[i];
    union { bf16_t b[4]; uint2 u; } p;
    p.b[0] = (bf16_t)v.x; p.b[1] = (bf16_t)v.y; p.b[2] = (bf16_t)v.z; p.b[3] = (bf16_t)v.w;
    ((uint2*)W2b)[i] = p.u;
  } else {
    // ---- heads concat ----
    const int i = (bid - 8704) * 256 + t;   // over 448*1024
    const int row = i >> 10, col = i & 1023;
    float v = 0.0f;
    if (row < 81) v = Wc[row * 1024 + col];
    else if (row < 401) v = Wr[(row - 81) * 1024 + col];
    Wcb[i] = (bf16_t)v;
    if (i < 448) bcat[i] = (i < 81) ? bc[i] : ((i < 401) ? br[i - 81] : 0.0f);
  }
}

// ---------------- ROI align on NHWC bf16; A[n][bin*256 + c] ----------------
__global__ __launch_bounds__(256) void roi_align_nhwc(const bf16_t* __restrict__ fb2,
                                                      const bf16_t* __restrict__ fb3,
                                                      const bf16_t* __restrict__ fb4,
                                                      const bf16_t* __restrict__ fb5,
                                                      const float* __restrict__ rois,
                                                      bf16_t* __restrict__ A) {
  const int n = blockIdx.x;
  const int t = threadIdx.x;
  const int b = n >> 9;
  const float4 box = ((const float4*)rois)[n];
  const float w = box.z - box.x, h = box.w - box.y;
  const int lv = (int)floorf(4.0f + log2f(sqrtf(w * h) / 224.0f + 1e-6f));
  bf16_t* Ar = A + (size_t)n * 12544;

  if (lv < 2 || lv > 5) {
    uint2 z; z.x = 0; z.y = 0;
    for (int j = t; j < 3136; j += 256) ((uint2*)Ar)[j] = z;
    return;
  }

  const bf16_t* F; int H, W; float scale;
  if (lv == 2)      { F = fb2; H = 200; W = 200; scale = 0.25f; }
  else if (lv == 3) { F = fb3; H = 100; W = 100; scale = 0.125f; }
  else if (lv == 4) { F = fb4; H = 50;  W = 50;  scale = 0.0625f; }
  else              { F = fb5; H = 25;  W = 25;  scale = 0.03125f; }
  F += (size_t)b * H * W * 256;

  __shared__ int   s_x0[14], s_xb[14], s_y0w[14], s_ybw[14];
  __shared__ float s_wx0[14], s_wx1[14], s_wy0[14], s_wy1[14];

  const float x1s = box.x * scale, y1s = box.y * scale;
  const float x2s = box.z * scale, y2s = box.w * scale;
  const float rw = fmaxf(x2s - x1s, 1.0f), rh = fmaxf(y2s - y1s, 1.0f);
  const float bwx = rw * (1.0f / 7.0f), bwy = rh * (1.0f / 7.0f);

  if (t < 14) {
    const int i2 = t >> 1, j = t & 1;
    const float off = (float)i2 + ((float)j + 0.5f) * 0.5f;
    float x = x1s + off * bwx;
    float vx = (x > -1.0f && x < (float)W) ? 1.0f : 0.0f;
    x = fminf(fmaxf(x, 0.0f), (float)(W - 1));
    float x0f = floorf(x);
    int x0 = (int)x0f;
    s_x0[t] = x0; s_xb[t] = min(x0 + 1, W - 1);
    float lx = x - x0f;
    s_wx0[t] = (1.0f - lx) * vx; s_wx1[t] = lx * vx;
    float y = y1s + off * bwy;
    float vy = (y > -1.0f && y < (float)H) ? 1.0f : 0.0f;
    y = fminf(fmaxf(y, 0.0f), (float)(H - 1));
    float y0f = floorf(y);
    int y0 = (int)y0f;
    s_y0w[t] = y0 * W; s_ybw[t] = min(y0 + 1, H - 1) * W;
    float ly = y - y0f;
    s_wy0[t] = (1.0f - ly) * vy; s_wy1[t] = ly * vy;
  }
  __syncthreads();

  const int wv = t >> 6, l = t & 63;
  const int c4 = l * 4;
  for (int bin = wv; bin < 49; bin += 4) {
    const int by = bin / 7, bx = bin - by * 7;
    float a0 = 0, a1 = 0, a2 = 0, a3 = 0;
#pragma unroll
    for (int sa = 0; sa < 2; sa++) {
      const int my = 2 * by + sa;
      const int y0w = s_y0w[my], ybw = s_ybw[my];
      const float wy0 = s_wy0[my], wy1 = s_wy1[my];
#pragma unroll
      for (int sb = 0; sb < 2; sb++) {
        const int mx = 2 * bx + sb;
        const int x0 = s_x0[mx], xb = s_xb[mx];
        const float w00 = wy0 * s_wx0[mx], w01 = wy0 * s_wx1[mx];
        const float w10 = wy1 * s_wx0[mx], w11 = wy1 * s_wx1[mx];
        bf16x4v v00 = *(const bf16x4v*)&F[(size_t)(y0w + x0) * 256 + c4];
        bf16x4v v01 = *(const bf16x4v*)&F[(size_t)(y0w + xb) * 256 + c4];
        bf16x4v v10 = *(const bf16x4v*)&F[(size_t)(ybw + x0) * 256 + c4];
        bf16x4v v11 = *(const bf16x4v*)&F[(size_t)(ybw + xb) * 256 + c4];
        a0 += w00 * (float)v00[0] + w01 * (float)v01[0] + w10 * (float)v10[0] + w11 * (float)v11[0];
        a1 += w00 * (float)v00[1] + w01 * (float)v01[1] + w10 * (float)v10[1] + w11 * (float)v11[1];
        a2 += w00 * (float)v00[2] + w01 * (float)v01[2] + w10 * (float)v10[2] + w11 * (float)v11[2];
        a3 += w00 * (float)v00[3] + w01 * (float)v01[3] + w10 * (float)v10[3] + w11 * (float)v11[3];
      }
    }
    union { bf16_t bb[4]; uint2 u; } pk;
    pk.bb[0] = (bf16_t)(a0 * 0.25f);
    pk.bb[1] = (bf16_t)(a1 * 0.25f);
    pk.bb[2] = (bf16_t)(a2 * 0.25f);
    pk.bb[3] = (bf16_t)(a3 * 0.25f);
    *(uint2*)&Ar[bin * 256 + c4] = pk.u;
  }
}

// ------- fc1: 128x128 tile, GLDS w/ swizzle, split-K=8, fp32 partials -------
// LDS chunk swizzle: physical 16B slot s at row r holds logical chunk s ^ ((r>>1)&3).
__global__ __launch_bounds__(256, 2) void gemm1_splitk(const bf16_t* __restrict__ A,
                                                       const bf16_t* __restrict__ B,
                                                       float* __restrict__ Cp) {
  __shared__ __align__(16) bf16_t As[128 * 32];
  __shared__ __align__(16) bf16_t Bs[128 * 32];
  const int t = threadIdx.x;
  const int w = t >> 6, l = t & 63;
  const int bm = blockIdx.x * 128, bn = blockIdx.y * 128;
  const int K = 12544;
  const int k0 = blockIdx.z * 1568;
  const int row1 = t >> 2;
  const int kc = ((t & 3) ^ ((t >> 3) & 3)) * 8;   // swizzled source chunk
  const bf16_t* gA1 = A + (size_t)(bm + row1) * K + k0 + kc;
  const bf16_t* gA2 = gA1 + (size_t)64 * K;
  const bf16_t* gB1 = B + (size_t)(bn + row1) * K + k0 + kc;
  const bf16_t* gB2 = gB1 + (size_t)64 * K;
  bf16_t* lA1 = As + w * 512;
  bf16_t* lA2 = As + 2048 + w * 512;
  bf16_t* lB1 = Bs + w * 512;
  bf16_t* lB2 = Bs + 2048 + w * 512;
  const int wm = (w >> 1) * 64, wn = (w & 1) * 64;
  const int rA = l & 15;
  const int kqs = (((l >> 4) ^ ((rA >> 1) & 3))) * 8;  // swizzled read chunk
  f32x4 acc[4][4] = {};

  for (int kk = 0; kk < 49; ++kk) {
    GLDS16(gA1, lA1); GLDS16(gA2, lA2);
    GLDS16(gB1, lB1); GLDS16(gB2, lB2);
    gA1 += 32; gA2 += 32; gB1 += 32; gB2 += 32;
    __syncthreads();
    bf16x8 a[4], b[4];
#pragma unroll
    for (int i = 0; i < 4; i++) {
      a[i] = *(const bf16x8*)&As[(wm + i * 16 + rA) * 32 + kqs];
      b[i] = *(const bf16x8*)&Bs[(wn + i * 16 + rA) * 32 + kqs];
    }
#pragma unroll
    for (int i = 0; i < 4; i++)
#pragma unroll
      for (int j = 0; j < 4; j++)
        acc[i][j] = __builtin_amdgcn_mfma_f32_16x16x32_bf16(a[i], b[j], acc[i][j], 0, 0, 0);
    __syncthreads();
  }

  const int q = l >> 4, cc = l & 15;
  float* Co = Cp + ((size_t)blockIdx.z << 20);
#pragma unroll
  for (int i = 0; i < 4; i++)
#pragma unroll
    for (int j = 0; j < 4; j++) {
      const int col = bn + wn + j * 16 + cc;
      const int r0 = bm + wm + i * 16 + q * 4;
#pragma unroll
      for (int r = 0; r < 4; r++)
        Co[(size_t)(r0 + r) * 1024 + col] = acc[i][j][r];
    }
}

// ------- split-K reduce + bias + relu + bf16 (1M outputs, 262144 float4 tasks) -------
__global__ __launch_bounds__(256) void reduce_fc1(const float* __restrict__ Cp,
                                                  const float* __restrict__ bias,
                                                  bf16_t* __restrict__ X) {
  const int i4 = blockIdx.x * 256 + threadIdx.x;
  const float4* C4 = (const float4*)Cp;
  float4 s = C4[i4];
#pragma unroll
  for (int z = 1; z < 8; z++) {
    float4 v = C4[(size_t)z * 262144 + i4];
    s.x += v.x; s.y += v.y; s.z += v.z; s.w += v.w;
  }
  const float4 bv = *(const float4*)&bias[(i4 & 255) * 4];
  union { bf16_t bb[4]; uint2 u; } pk;
  pk.bb[0] = (bf16_t)fmaxf(s.x + bv.x, 0.0f);
  pk.bb[1] = (bf16_t)fmaxf(s.y + bv.y, 0.0f);
  pk.bb[2] = (bf16_t)fmaxf(s.z + bv.z, 0.0f);
  pk.bb[3] = (bf16_t)fmaxf(s.w + bv.w, 0.0f);
  ((uint2*)X)[i4] = pk.u;
}

// ---------------- GEMM (64x64 tile, swizzled LDS): C = epi(A x B^T + bias) ----------------
template <int MODE>
__global__ __launch_bounds__(256) void gemm_bt(const bf16_t* __restrict__ A,
                                               const bf16_t* __restrict__ B,
                                               const float* __restrict__ bias,
                                               void* __restrict__ out,
                                               int M, int N, int K) {
  __shared__ __align__(16) bf16_t As[64 * 32];
  __shared__ __align__(16) bf16_t Bs[64 * 32];
  const int t = threadIdx.x;
  const int wv = t >> 6, l = t & 63;
  const int bm = blockIdx.x * 64, bn = blockIdx.y * 64;
  const int wm = (wv >> 1) * 32, wn = (wv & 1) * 32;

  const int srow = t >> 2;
  const int skc = (t & 3) * 8;                               // global chunk (contiguous)
  const int sst = ((t & 3) ^ ((t >> 3) & 3)) * 8;            // swizzled LDS store slot
  const bf16_t* ga = A + (size_t)(bm + srow) * K + skc;
  const bf16_t* gb = B + (size_t)(bn + srow) * K + skc;

  uint4 ra = *(const uint4*)ga;
  uint4 rb = *(const uint4*)gb;
  f32x4 acc[2][2] = {};

  const int nIter = K >> 5;
  const int rA = l & 15;
  const int kqs = (((l >> 4) ^ ((rA >> 1) & 3))) * 8;
  for (int i = 0; i < nIter; ++i) {
    ga += 32; gb += 32;
    *(uint4*)&As[srow * 32 + sst] = ra;
    *(uint4*)&Bs[srow * 32 + sst] = rb;
    __syncthreads();
    if (i + 1 < nIter) { ra = *(const uint4*)ga; rb = *(const uint4*)gb; }
    bf16x8 a0 = *(const bf16x8*)&As[(wm + rA) * 32 + kqs];
    bf16x8 a1 = *(const bf16x8*)&As[(wm + 16 + rA) * 32 + kqs];
    bf16x8 b0 = *(const bf16x8*)&Bs[(wn + rA) * 32 + kqs];
    bf16x8 b1 = *(const bf16x8*)&Bs[(wn + 16 + rA) * 32 + kqs];
    acc[0][0] = __builtin_amdgcn_mfma_f32_16x16x32_bf16(a0, b0, acc[0][0], 0, 0, 0);
    acc[0][1] = __builtin_amdgcn_mfma_f32_16x16x32_bf16(a0, b1, acc[0][1], 0, 0, 0);
    acc[1][0] = __builtin_amdgcn_mfma_f32_16x16x32_bf16(a1, b0, acc[1][0], 0, 0, 0);
    acc[1][1] = __builtin_amdgcn_mfma_f32_16x16x32_bf16(a1, b1, acc[1][1], 0, 0, 0);
    __syncthreads();
  }

  const int q = l >> 4;
  const int cc = l & 15;
#pragma unroll
  for (int i2 = 0; i2 < 2; i2++) {
#pragma unroll
    for (int j2 = 0; j2 < 2; j2++) {
      const int col = bn + wn + j2 * 16 + cc;
      const int row0 = bm + wm + i2 * 16 + q * 4;
      const float bv = bias[col];
#pragma unroll
      for (int r = 0; r < 4; r++) {
        float v = acc[i2][j2][r] + bv;
        const int row = row0 + r;
        if (MODE == 0) {
          v = fmaxf(v, 0.0f);
          ((bf16_t*)out)[(size_t)row * N + col] = (bf16_t)v;
        } else {
          if (col < 81)       ((float*)out)[(size_t)row * 81 + col] = v;
          else if (col < 401) ((float*)out)[82944 + (size_t)row * 320 + (col - 81)] = v;
        }
      }
    }
  }
}

extern "C" void kernel_launch(void* const* d_in, const int* in_sizes, int n_in,
                              void* d_out, int out_size, void* d_ws, size_t ws_size,
                              hipStream_t stream) {
  const float* f2   = (const float*)d_in[0];
  const float* f3   = (const float*)d_in[1];
  const float* f4   = (const float*)d_in[2];
  const float* f5   = (const float*)d_in[3];
  const float* rois = (const float*)d_in[4];
  const float* W1   = (const float*)d_in[5];
  const float* b1   = (const float*)d_in[6];
  const float* W2   = (const float*)d_in[7];
  const float* b2   = (const float*)d_in[8];
  const float* Wc   = (const float*)d_in[9];
  const float* bc   = (const float*)d_in[10];
  const float* Wr   = (const float*)d_in[11];
  const float* br   = (const float*)d_in[12];

  char* ws = (char*)d_ws;
  bf16_t* Ab   = (bf16_t*)(ws);                 // 1024x12544 bf16
  bf16_t* W1b  = (bf16_t*)(ws + 25690112);      // 1024x12544 bf16 (K-permuted)
  bf16_t* X1b  = (bf16_t*)(ws + 51380224);      // 1024x1024 bf16
  bf16_t* W2b  = (bf16_t*)(ws + 53477376);      // 1024x1024 bf16
  bf16_t* X2b  = (bf16_t*)(ws + 55574528);      // 1024x1024 bf16
  bf16_t* Wcb  = (bf16_t*)(ws + 57671680);      // 448x1024 bf16
  float*  bcat = (float*)(ws + 58589184);       // 448 fp32
  bf16_t* FT   = (bf16_t*)(ws + 58591232);      // NHWC feats bf16 (54.4 MB)
  float*  Cp   = (float*)(ws + 58591232);       // fc1 split-K partials (aliases FT)
  bf16_t* FT2 = FT;
  bf16_t* FT3 = FT + 20480000;
  bf16_t* FT4 = FT + 25600000;
  bf16_t* FT5 = FT + 26880000;

  prep_all<<<10496, 256, 0, stream>>>(f2, f3, f4, f5, W1, W2, Wc, bc, Wr, br,
                                      FT2, FT3, FT4, FT5, W1b, W2b, Wcb, bcat);
  roi_align_nhwc<<<1024, 256, 0, stream>>>(FT2, FT3, FT4, FT5, rois, Ab);
  gemm1_splitk<<<dim3(8, 8, 8), 256, 0, stream>>>(Ab, W1b, Cp);
  reduce_fc1<<<1024, 256, 0, stream>>>(Cp, b1, X1b);
  gemm_bt<0><<<dim3(16, 16), 256, 0, stream>>>(X1b, W2b, b2, (void*)X2b, 1024, 1024, 1024);
  gemm_bt<1><<<dim3(16, 7), 256, 0, stream>>>(X2b, Wcb, bcat, d_out, 1024, 448, 1024);
}

// Round 5
// 323.211 us; speedup vs baseline: 1.5143x; 1.0118x over previous
//
#include <hip/hip_runtime.h>

typedef __bf16 bf16_t;
typedef __bf16 bf16x8 __attribute__((ext_vector_type(8)));
typedef float f32x4 __attribute__((ext_vector_type(4)));

#define GLDS16(g, l)                                                            \
  __builtin_amdgcn_global_load_lds((const __attribute__((address_space(1))) void*)(g), \
                                   (__attribute__((address_space(3))) void*)(l), 16, 0, 0)

// ================= fused prep: transposes + weight cvt/permute (all vectorized) =================
// block ranges: [0,5000) f2 T, [5000,6256) f3 T, [6256,6576) f4 T, [6576,6656) f5 T,
//               [6656,8704) W1 permute half-rows, [8704,9728) W2 cvt, [9728,10176) heads concat
__global__ __launch_bounds__(256) void prep_all(const float* __restrict__ f2,
                                                const float* __restrict__ f3,
                                                const float* __restrict__ f4,
                                                const float* __restrict__ f5,
                                                const float* __restrict__ W1,
                                                const float* __restrict__ W2,
                                                const float* __restrict__ Wc,
                                                const float* __restrict__ bc,
                                                const float* __restrict__ Wr,
                                                const float* __restrict__ br,
                                                bf16_t* __restrict__ FT2,
                                                bf16_t* __restrict__ FT3,
                                                bf16_t* __restrict__ FT4,
                                                bf16_t* __restrict__ FT5,
                                                bf16_t* __restrict__ W1p,
                                                bf16_t* __restrict__ W2b,
                                                bf16_t* __restrict__ Wcb,
                                                float* __restrict__ bcat) {
  __shared__ __align__(16) char smraw[16640];
  const int bid = blockIdx.x;
  const int t = threadIdx.x;

  if (bid < 6656) {
    // ---- NCHW fp32 -> NHWC bf16 transpose, 64px x 64ch tile ----
    float* tile = (float*)smraw;   // 64*65 floats
    const float* src; bf16_t* dst; int P, rel, ptiles;
    if (bid < 5000)      { src = f2; dst = FT2; P = 40000; rel = bid;        ptiles = 625; }
    else if (bid < 6256) { src = f3; dst = FT3; P = 10000; rel = bid - 5000; ptiles = 157; }
    else if (bid < 6576) { src = f4; dst = FT4; P = 2500;  rel = bid - 6256; ptiles = 40; }
    else                 { src = f5; dst = FT5; P = 625;   rel = bid - 6576; ptiles = 10; }
    const int pt = rel % ptiles;
    const int cb = (rel / ptiles) & 3;
    const int b = rel / (ptiles * 4);
    const int p0 = pt * 64, c0 = cb * 64;
    const float* s = src + (size_t)(b * 256 + c0) * P;
    if (p0 + 64 <= P && (P & 3) == 0) {
      // fast path: float4 reads, 16 lanes x 4 float4 = 256B contiguous per phase
      const int chb = t >> 4, px4 = (t & 15) * 4;
#pragma unroll
      for (int it = 0; it < 4; ++it) {
        const int ch = it * 16 + chb;
        float4 v = *(const float4*)&s[(size_t)ch * P + p0 + px4];
        float* tr = &tile[ch * 65 + px4];
        tr[0] = v.x; tr[1] = v.y; tr[2] = v.z; tr[3] = v.w;
      }
    } else {
      // slow path (partial / misaligned tiles only)
#pragma unroll
      for (int it = 0; it < 16; ++it) {
        const int ch = it * 4 + (t >> 6);
        const int px = t & 63;
        float v = 0.0f;
        if (p0 + px < P) v = s[(size_t)ch * P + p0 + px];
        tile[ch * 65 + px] = v;
      }
    }
    __syncthreads();
    bf16_t* d = dst + ((size_t)b * P + p0) * 256 + c0;
#pragma unroll
    for (int it = 0; it < 4; ++it) {
      const int px = it * 16 + (t >> 4);
      const int ch4 = (t & 15) * 4;
      if (p0 + px < P) {
        union { bf16_t bb[4]; uint2 u; } pk;
#pragma unroll
        for (int k2 = 0; k2 < 4; k2++) pk.bb[k2] = (bf16_t)tile[(ch4 + k2) * 65 + px];
        *(uint2*)&d[(size_t)px * 256 + ch4] = pk.u;
      }
    }
  } else if (bid < 8704) {
    // ---- W1 half-row: fp32 -> bf16, K permuted c*49+bin -> bin*256+c ----
    // phase 1: linear float4 read -> bf16 -> linear LDS; phase 2: gather from LDS, coalesced write
    bf16_t* lin = (bf16_t*)smraw;     // 6272 bf16 (c-major: lc*49+bin)
    const int idx = bid - 6656;
    const int row = idx >> 1, c0 = (idx & 1) * 128;
    const float* src = W1 + (size_t)row * 12544 + (size_t)c0 * 49;
    for (int i = t; i < 1568; i += 256) {
      float4 v = ((const float4*)src)[i];
      union { bf16_t bb[4]; uint2 u; } pk;
      pk.bb[0] = (bf16_t)v.x; pk.bb[1] = (bf16_t)v.y;
      pk.bb[2] = (bf16_t)v.z; pk.bb[3] = (bf16_t)v.w;
      *(uint2*)&lin[i * 4] = pk.u;
    }
    __syncthreads();
    bf16_t* dst = W1p + (size_t)row * 12544 + c0;
    for (int j4 = t; j4 < 1568; j4 += 256) {
      const int bin = j4 >> 5;
      const int lc = (j4 & 31) * 4;
      union { bf16_t bb[4]; uint2 u; } pk;
#pragma unroll
      for (int k2 = 0; k2 < 4; k2++) pk.bb[k2] = lin[(lc + k2) * 49 + bin];
      *(uint2*)&dst[bin * 256 + lc] = pk.u;
    }
  } else if (bid < 9728) {
    // ---- W2 fp32 -> bf16 ----
    const int i = (bid - 8704) * 256 + t;   // < 262144 float4s
    float4 v = ((const float4*)W2)[i];
    union { bf16_t b[4]; uint2 u; } p;
    p.b[0] = (bf16_t)v.x; p.b[1] = (bf16_t)v.y; p.b[2] = (bf16_t)v.z; p.b[3] = (bf16_t)v.w;
    ((uint2*)W2b)[i] = p.u;
  } else {
    // ---- heads concat (float4 read, uint2 write) ----
    const int q = (bid - 9728) * 256 + t;   // < 114688 quads
    const int row = q >> 8, col4 = (q & 255) * 4;
    float4 v = {0.0f, 0.0f, 0.0f, 0.0f};
    if (row < 81) v = *(const float4*)&Wc[row * 1024 + col4];
    else if (row < 401) v = *(const float4*)&Wr[(row - 81) * 1024 + col4];
    union { bf16_t b[4]; uint2 u; } p;
    p.b[0] = (bf16_t)v.x; p.b[1] = (bf16_t)v.y; p.b[2] = (bf16_t)v.z; p.b[3] = (bf16_t)v.w;
    ((uint2*)Wcb)[q] = p.u;
    if (q < 448) bcat[q] = (q < 81) ? bc[q] : ((q < 401) ? br[q - 81] : 0.0f);
  }
}

// ---------------- ROI align on NHWC bf16; A[n][bin*256 + c]; 16B loads, half-wave/bin ----------------
__global__ __launch_bounds__(256) void roi_align_nhwc(const bf16_t* __restrict__ fb2,
                                                      const bf16_t* __restrict__ fb3,
                                                      const bf16_t* __restrict__ fb4,
                                                      const bf16_t* __restrict__ fb5,
                                                      const float* __restrict__ rois,
                                                      bf16_t* __restrict__ A) {
  const int n = blockIdx.x;
  const int t = threadIdx.x;
  const int b = n >> 9;
  const float4 box = ((const float4*)rois)[n];
  const float w = box.z - box.x, h = box.w - box.y;
  const int lv = (int)floorf(4.0f + log2f(sqrtf(w * h) / 224.0f + 1e-6f));
  bf16_t* Ar = A + (size_t)n * 12544;

  if (lv < 2 || lv > 5) {
    uint4 z = {0, 0, 0, 0};
    for (int j = t; j < 1568; j += 256) ((uint4*)Ar)[j] = z;
    return;
  }

  const bf16_t* F; int H, W; float scale;
  if (lv == 2)      { F = fb2; H = 200; W = 200; scale = 0.25f; }
  else if (lv == 3) { F = fb3; H = 100; W = 100; scale = 0.125f; }
  else if (lv == 4) { F = fb4; H = 50;  W = 50;  scale = 0.0625f; }
  else              { F = fb5; H = 25;  W = 25;  scale = 0.03125f; }
  F += (size_t)b * H * W * 256;

  __shared__ int   s_x0[14], s_xb[14], s_y0w[14], s_ybw[14];
  __shared__ float s_wx0[14], s_wx1[14], s_wy0[14], s_wy1[14];

  const float x1s = box.x * scale, y1s = box.y * scale;
  const float x2s = box.z * scale, y2s = box.w * scale;
  const float rw = fmaxf(x2s - x1s, 1.0f), rh = fmaxf(y2s - y1s, 1.0f);
  const float bwx = rw * (1.0f / 7.0f), bwy = rh * (1.0f / 7.0f);

  if (t < 14) {
    const int i2 = t >> 1, j = t & 1;
    const float off = (float)i2 + ((float)j + 0.5f) * 0.5f;
    float x = x1s + off * bwx;
    float vx = (x > -1.0f && x < (float)W) ? 1.0f : 0.0f;
    x = fminf(fmaxf(x, 0.0f), (float)(W - 1));
    float x0f = floorf(x);
    int x0 = (int)x0f;
    s_x0[t] = x0; s_xb[t] = min(x0 + 1, W - 1);
    float lx = x - x0f;
    s_wx0[t] = (1.0f - lx) * vx; s_wx1[t] = lx * vx;
    float y = y1s + off * bwy;
    float vy = (y > -1.0f && y < (float)H) ? 1.0f : 0.0f;
    y = fminf(fmaxf(y, 0.0f), (float)(H - 1));
    float y0f = floorf(y);
    int y0 = (int)y0f;
    s_y0w[t] = y0 * W; s_ybw[t] = min(y0 + 1, H - 1) * W;
    float ly = y - y0f;
    s_wy0[t] = (1.0f - ly) * vy; s_wy1[t] = ly * vy;
  }
  __syncthreads();

  const int wv = t >> 6, l = t & 63;
  const int half = l >> 5, c8 = (l & 31) * 8;
  for (int p = wv; p < 25; p += 4) {
    const int bin = 2 * p + half;
    if (bin >= 49) continue;           // only p=24, half=1
    const int by = bin / 7, bx = bin - by * 7;
    float a[8] = {};
#pragma unroll
    for (int sa = 0; sa < 2; sa++) {
      const int my = 2 * by + sa;
      const int y0w = s_y0w[my], ybw = s_ybw[my];
      const float wy0 = s_wy0[my], wy1 = s_wy1[my];
#pragma unroll
      for (int sb = 0; sb < 2; sb++) {
        const int mx = 2 * bx + sb;
        const int x0 = s_x0[mx], xb = s_xb[mx];
        const float w00 = wy0 * s_wx0[mx], w01 = wy0 * s_wx1[mx];
        const float w10 = wy1 * s_wx0[mx], w11 = wy1 * s_wx1[mx];
        bf16x8 v00 = *(const bf16x8*)&F[(size_t)(y0w + x0) * 256 + c8];
        bf16x8 v01 = *(const bf16x8*)&F[(size_t)(y0w + xb) * 256 + c8];
        bf16x8 v10 = *(const bf16x8*)&F[(size_t)(ybw + x0) * 256 + c8];
        bf16x8 v11 = *(const bf16x8*)&F[(size_t)(ybw + xb) * 256 + c8];
#pragma unroll
        for (int k2 = 0; k2 < 8; k2++)
          a[k2] += w00 * (float)v00[k2] + w01 * (float)v01[k2]
                 + w10 * (float)v10[k2] + w11 * (float)v11[k2];
      }
    }
    union { bf16_t bb[8]; uint4 u; } pk;
#pragma unroll
    for (int k2 = 0; k2 < 8; k2++) pk.bb[k2] = (bf16_t)(a[k2] * 0.25f);
    *(uint4*)&Ar[bin * 256 + c8] = pk.u;
  }
}

// ------- fc1: 64x128 tile, GLDS w/ swizzle, split-K=8, fp32 partials; grid (16,8,8) -------
__global__ __launch_bounds__(256, 4) void gemm1_splitk(const bf16_t* __restrict__ A,
                                                       const bf16_t* __restrict__ B,
                                                       float* __restrict__ Cp) {
  __shared__ __align__(16) bf16_t As[64 * 32];
  __shared__ __align__(16) bf16_t Bs[128 * 32];
  const int t = threadIdx.x;
  const int w = t >> 6, l = t & 63;
  const int bm = blockIdx.x * 64, bn = blockIdx.y * 128;
  const int K = 12544;
  const int k0 = blockIdx.z * 1568;
  const int row = t >> 2;
  const int kc = ((t & 3) ^ ((t >> 3) & 3)) * 8;   // swizzled source chunk
  const bf16_t* gA  = A + (size_t)(bm + row) * K + k0 + kc;
  const bf16_t* gB1 = B + (size_t)(bn + row) * K + k0 + kc;
  const bf16_t* gB2 = gB1 + (size_t)64 * K;
  bf16_t* lA  = As + w * 512;
  bf16_t* lB1 = Bs + w * 512;
  bf16_t* lB2 = Bs + 2048 + w * 512;
  const int wm = (w & 1) * 32, wn = (w >> 1) * 64;
  const int rA = l & 15;
  const int kqs = (((l >> 4) ^ ((rA >> 1) & 3))) * 8;  // swizzled read chunk
  f32x4 acc[2][4] = {};

  for (int kk = 0; kk < 49; ++kk) {
    GLDS16(gA, lA); GLDS16(gB1, lB1); GLDS16(gB2, lB2);
    gA += 32; gB1 += 32; gB2 += 32;
    __syncthreads();
    bf16x8 a[2], b[4];
#pragma unroll
    for (int i = 0; i < 2; i++) a[i] = *(const bf16x8*)&As[(wm + i * 16 + rA) * 32 + kqs];
#pragma unroll
    for (int j = 0; j < 4; j++) b[j] = *(const bf16x8*)&Bs[(wn + j * 16 + rA) * 32 + kqs];
#pragma unroll
    for (int i = 0; i < 2; i++)
#pragma unroll
      for (int j = 0; j < 4; j++)
        acc[i][j] = __builtin_amdgcn_mfma_f32_16x16x32_bf16(a[i], b[j], acc[i][j], 0, 0, 0);
    __syncthreads();
  }

  const int q = l >> 4, cc = l & 15;
  float* Co = Cp + ((size_t)blockIdx.z << 20);
#pragma unroll
  for (int i = 0; i < 2; i++)
#pragma unroll
    for (int j = 0; j < 4; j++) {
      const int col = bn + wn + j * 16 + cc;
      const int r0 = bm + wm + i * 16 + q * 4;
#pragma unroll
      for (int r = 0; r < 4; r++)
        Co[(size_t)(r0 + r) * 1024 + col] = acc[i][j][r];
    }
}

// ------- split-K reduce + bias + relu + bf16 (1M outputs, 262144 float4 tasks) -------
__global__ __launch_bounds__(256) void reduce_fc1(const float* __restrict__ Cp,
                                                  const float* __restrict__ bias,
                                                  bf16_t* __restrict__ X) {
  const int i4 = blockIdx.x * 256 + threadIdx.x;
  const float4* C4 = (const float4*)Cp;
  float4 s = C4[i4];
#pragma unroll
  for (int z = 1; z < 8; z++) {
    float4 v = C4[(size_t)z * 262144 + i4];
    s.x += v.x; s.y += v.y; s.z += v.z; s.w += v.w;
  }
  const float4 bv = *(const float4*)&bias[(i4 & 255) * 4];
  union { bf16_t bb[4]; uint2 u; } pk;
  pk.bb[0] = (bf16_t)fmaxf(s.x + bv.x, 0.0f);
  pk.bb[1] = (bf16_t)fmaxf(s.y + bv.y, 0.0f);
  pk.bb[2] = (bf16_t)fmaxf(s.z + bv.z, 0.0f);
  pk.bb[3] = (bf16_t)fmaxf(s.w + bv.w, 0.0f);
  ((uint2*)X)[i4] = pk.u;
}

// ---------------- GEMM (64x64 tile, swizzled LDS): C = epi(A x B^T + bias) ----------------
template <int MODE>
__global__ __launch_bounds__(256) void gemm_bt(const bf16_t* __restrict__ A,
                                               const bf16_t* __restrict__ B,
                                               const float* __restrict__ bias,
                                               void* __restrict__ out,
                                               int M, int N, int K) {
  __shared__ __align__(16) bf16_t As[64 * 32];
  __shared__ __align__(16) bf16_t Bs[64 * 32];
  const int t = threadIdx.x;
  const int wv = t >> 6, l = t & 63;
  const int bm = blockIdx.x * 64, bn = blockIdx.y * 64;
  const int wm = (wv >> 1) * 32, wn = (wv & 1) * 32;

  const int srow = t >> 2;
  const int skc = (t & 3) * 8;
  const int sst = ((t & 3) ^ ((t >> 3) & 3)) * 8;
  const bf16_t* ga = A + (size_t)(bm + srow) * K + skc;
  const bf16_t* gb = B + (size_t)(bn + srow) * K + skc;

  uint4 ra = *(const uint4*)ga;
  uint4 rb = *(const uint4*)gb;
  f32x4 acc[2][2] = {};

  const int nIter = K >> 5;
  const int rA = l & 15;
  const int kqs = (((l >> 4) ^ ((rA >> 1) & 3))) * 8;
  for (int i = 0; i < nIter; ++i) {
    ga += 32; gb += 32;
    *(uint4*)&As[srow * 32 + sst] = ra;
    *(uint4*)&Bs[srow * 32 + sst] = rb;
    __syncthreads();
    if (i + 1 < nIter) { ra = *(const uint4*)ga; rb = *(const uint4*)gb; }
    bf16x8 a0 = *(const bf16x8*)&As[(wm + rA) * 32 + kqs];
    bf16x8 a1 = *(const bf16x8*)&As[(wm + 16 + rA) * 32 + kqs];
    bf16x8 b0 = *(const bf16x8*)&Bs[(wn + rA) * 32 + kqs];
    bf16x8 b1 = *(const bf16x8*)&Bs[(wn + 16 + rA) * 32 + kqs];
    acc[0][0] = __builtin_amdgcn_mfma_f32_16x16x32_bf16(a0, b0, acc[0][0], 0, 0, 0);
    acc[0][1] = __builtin_amdgcn_mfma_f32_16x16x32_bf16(a0, b1, acc[0][1], 0, 0, 0);
    acc[1][0] = __builtin_amdgcn_mfma_f32_16x16x32_bf16(a1, b0, acc[1][0], 0, 0, 0);
    acc[1][1] = __builtin_amdgcn_mfma_f32_16x16x32_bf16(a1, b1, acc[1][1], 0, 0, 0);
    __syncthreads();
  }

  const int q = l >> 4;
  const int cc = l & 15;
#pragma unroll
  for (int i2 = 0; i2 < 2; i2++) {
#pragma unroll
    for (int j2 = 0; j2 < 2; j2++) {
      const int col = bn + wn + j2 * 16 + cc;
      const int row0 = bm + wm + i2 * 16 + q * 4;
      const float bv = bias[col];
#pragma unroll
      for (int r = 0; r < 4; r++) {
        float v = acc[i2][j2][r] + bv;
        const int row = row0 + r;
        if (MODE == 0) {
          v = fmaxf(v, 0.0f);
          ((bf16_t*)out)[(size_t)row * N + col] = (bf16_t)v;
        } else {
          if (col < 81)       ((float*)out)[(size_t)row * 81 + col] = v;
          else if (col < 401) ((float*)out)[82944 + (size_t)row * 320 + (col - 81)] = v;
        }
      }
    }
  }
}

extern "C" void kernel_launch(void* const* d_in, const int* in_sizes, int n_in,
                              void* d_out, int out_size, void* d_ws, size_t ws_size,
                              hipStream_t stream) {
  const float* f2   = (const float*)d_in[0];
  const float* f3   = (const float*)d_in[1];
  const float* f4   = (const float*)d_in[2];
  const float* f5   = (const float*)d_in[3];
  const float* rois = (const float*)d_in[4];
  const float* W1   = (const float*)d_in[5];
  const float* b1   = (const float*)d_in[6];
  const float* W2   = (const float*)d_in[7];
  const float* b2   = (const float*)d_in[8];
  const float* Wc   = (const float*)d_in[9];
  const float* bc   = (const float*)d_in[10];
  const float* Wr   = (const float*)d_in[11];
  const float* br   = (const float*)d_in[12];

  char* ws = (char*)d_ws;
  bf16_t* Ab   = (bf16_t*)(ws);                 // 1024x12544 bf16
  bf16_t* W1b  = (bf16_t*)(ws + 25690112);      // 1024x12544 bf16 (K-permuted)
  bf16_t* X1b  = (bf16_t*)(ws + 51380224);      // 1024x1024 bf16
  bf16_t* W2b  = (bf16_t*)(ws + 53477376);      // 1024x1024 bf16
  bf16_t* X2b  = (bf16_t*)(ws + 55574528);      // 1024x1024 bf16
  bf16_t* Wcb  = (bf16_t*)(ws + 57671680);      // 448x1024 bf16
  float*  bcat = (float*)(ws + 58589184);       // 448 fp32
  bf16_t* FT   = (bf16_t*)(ws + 58591232);      // NHWC feats bf16 (54.4 MB)
  float*  Cp   = (float*)(ws + 58591232);       // fc1 split-K partials (aliases FT)
  bf16_t* FT2 = FT;
  bf16_t* FT3 = FT + 20480000;
  bf16_t* FT4 = FT + 25600000;
  bf16_t* FT5 = FT + 26880000;

  prep_all<<<10176, 256, 0, stream>>>(f2, f3, f4, f5, W1, W2, Wc, bc, Wr, br,
                                      FT2, FT3, FT4, FT5, W1b, W2b, Wcb, bcat);
  roi_align_nhwc<<<1024, 256, 0, stream>>>(FT2, FT3, FT4, FT5, rois, Ab);
  gemm1_splitk<<<dim3(16, 8, 8), 256, 0, stream>>>(Ab, W1b, Cp);
  reduce_fc1<<<1024, 256, 0, stream>>>(Cp, b1, X1b);
  gemm_bt<0><<<dim3(16, 16), 256, 0, stream>>>(X1b, W2b, b2, (void*)X2b, 1024, 1024, 1024);
  gemm_bt<1><<<dim3(16, 7), 256, 0, stream>>>(X2b, Wcb, bcat, d_out, 1024, 448, 1024);
}

// Round 6
// 315.402 us; speedup vs baseline: 1.5518x; 1.0248x over previous
//
#include <hip/hip_runtime.h>

typedef __bf16 bf16_t;
typedef __bf16 bf16x8 __attribute__((ext_vector_type(8)));
typedef float f32x4 __attribute__((ext_vector_type(4)));

#define GLDS16(g, l)                                                            \
  __builtin_amdgcn_global_load_lds((const __attribute__((address_space(1))) void*)(g), \
                                   (__attribute__((address_space(3))) void*)(l), 16, 0, 0)

__device__ __forceinline__ float f4c(const float4& f, int k) {
  return k == 0 ? f.x : (k == 1 ? f.y : (k == 2 ? f.z : f.w));
}

// ================= fused prep =================
// [0,1256) f2 T, [1256,1576) f3 T, [1576,1656) f4 T, [1656,1680) f5 T,
// [1680,3728) W1 permute half-rows, [3728,4752) W2 cvt, [4752,5200) heads concat
// Transpose: 64ch x 256px tile, register 4x4 transpose, XOR-swizzled LDS, all-vector LDS ops.
__global__ __launch_bounds__(256, 4) void prep_all(const float* __restrict__ f2,
                                                   const float* __restrict__ f3,
                                                   const float* __restrict__ f4,
                                                   const float* __restrict__ f5,
                                                   const float* __restrict__ W1,
                                                   const float* __restrict__ W2,
                                                   const float* __restrict__ Wc,
                                                   const float* __restrict__ bc,
                                                   const float* __restrict__ Wr,
                                                   const float* __restrict__ br,
                                                   bf16_t* __restrict__ FT2,
                                                   bf16_t* __restrict__ FT3,
                                                   bf16_t* __restrict__ FT4,
                                                   bf16_t* __restrict__ FT5,
                                                   bf16_t* __restrict__ W1p,
                                                   bf16_t* __restrict__ W2b,
                                                   bf16_t* __restrict__ Wcb,
                                                   float* __restrict__ bcat) {
  __shared__ __align__(16) char smraw[32768];
  const int bid = blockIdx.x;
  const int t = threadIdx.x;

  if (bid < 1680) {
    // ---- NCHW fp32 -> NHWC bf16 transpose, 64ch x 256px tile ----
    const float* src; bf16_t* dst; int P, rel, tp;
    if (bid < 1256)      { src = f2; dst = FT2; P = 40000; rel = bid;        tp = 157; }
    else if (bid < 1576) { src = f3; dst = FT3; P = 10000; rel = bid - 1256; tp = 40; }
    else if (bid < 1656) { src = f4; dst = FT4; P = 2500;  rel = bid - 1576; tp = 10; }
    else                 { src = f5; dst = FT5; P = 625;   rel = bid - 1656; tp = 3; }
    const int pt = rel % tp;
    const int cb = (rel / tp) & 3;
    const int b = rel / (tp * 4);
    const int p0 = pt * 256, c0 = cb * 64;
    const float* s = src + (size_t)(b * 256 + c0) * P;
    bf16_t* lds = (bf16_t*)smraw;    // [px 0..255][64ch], row = 128B, 16B-chunk XOR swizzle

    const int g = t >> 4;            // ch group: local ch = 4g..4g+3
    const int wbase = t & 15;        // px window base

    // phase 1a: issue all 16 loads (kept in registers -> 16 outstanding)
    float4 v[4][4];
#pragma unroll
    for (int j = 0; j < 4; j++) {
      const int w = wbase + 16 * j;
      const int px0 = p0 + 4 * w;
#pragma unroll
      for (int r = 0; r < 4; r++) {
        const float* rowp = s + (size_t)(4 * g + r) * P + px0;
        if (px0 + 4 <= P) {
          v[j][r] = *(const float4*)rowp;
        } else {
          float4 z = {0.f, 0.f, 0.f, 0.f};
          if (px0 < P) {
            for (int e = 0; e < 4; e++) if (px0 + e < P) (&z.x)[e] = rowp[e];
          }
          v[j][r] = z;
        }
      }
    }
    // phase 1b: 4x4 register transpose -> swizzled ds_write_b64
#pragma unroll
    for (int j = 0; j < 4; j++) {
      const int w = wbase + 16 * j;
#pragma unroll
      for (int k = 0; k < 4; k++) {
        const int px = 4 * w + k;            // tile-relative px
        union { bf16_t bb[4]; uint2 u; } pk;
#pragma unroll
        for (int r = 0; r < 4; r++) pk.bb[r] = (bf16_t)f4c(v[j][r], k);
        const int phys_c = (g >> 1) ^ ((px >> 1) & 7);
        *(uint2*)&smraw[px * 128 + phys_c * 16 + (g & 1) * 8] = pk.u;
      }
    }
    __syncthreads();
    // phase 2: ds_read_b128 rows -> coalesced 16B global writes
    bf16_t* d = dst + ((size_t)b * P + p0) * 256 + c0;
#pragma unroll
    for (int pass = 0; pass < 8; pass++) {
      const int px = pass * 32 + (t >> 3);
      const int c = t & 7;
      if (p0 + px < P) {
        const int phys_c = c ^ ((px >> 1) & 7);
        uint4 val = *(const uint4*)&smraw[px * 128 + phys_c * 16];
        *(uint4*)&d[(size_t)px * 256 + c * 8] = val;
      }
    }
  } else if (bid < 3728) {
    // ---- W1 half-row: fp32 -> bf16, K permuted c*49+bin -> bin*256+c ----
    bf16_t* lin = (bf16_t*)smraw;     // 6272 bf16 (c-major: lc*49+bin)
    const int idx = bid - 1680;
    const int row = idx >> 1, c0 = (idx & 1) * 128;
    const float* src = W1 + (size_t)row * 12544 + (size_t)c0 * 49;
    for (int i = t; i < 1568; i += 256) {
      float4 v = ((const float4*)src)[i];
      union { bf16_t bb[4]; uint2 u; } pk;
      pk.bb[0] = (bf16_t)v.x; pk.bb[1] = (bf16_t)v.y;
      pk.bb[2] = (bf16_t)v.z; pk.bb[3] = (bf16_t)v.w;
      *(uint2*)&lin[i * 4] = pk.u;
    }
    __syncthreads();
    bf16_t* dst = W1p + (size_t)row * 12544 + c0;
    for (int j4 = t; j4 < 1568; j4 += 256) {
      const int bin = j4 >> 5;
      const int lc = (j4 & 31) * 4;
      union { bf16_t bb[4]; uint2 u; } pk;
#pragma unroll
      for (int k2 = 0; k2 < 4; k2++) pk.bb[k2] = lin[(lc + k2) * 49 + bin];
      *(uint2*)&dst[bin * 256 + lc] = pk.u;
    }
  } else if (bid < 4752) {
    // ---- W2 fp32 -> bf16 ----
    const int i = (bid - 3728) * 256 + t;   // < 262144 float4s
    float4 v = ((const float4*)W2)[i];
    union { bf16_t b[4]; uint2 u; } p;
    p.b[0] = (bf16_t)v.x; p.b[1] = (bf16_t)v.y; p.b[2] = (bf16_t)v.z; p.b[3] = (bf16_t)v.w;
    ((uint2*)W2b)[i] = p.u;
  } else {
    // ---- heads concat (float4 read, uint2 write) ----
    const int q = (bid - 4752) * 256 + t;   // < 114688 quads
    const int row = q >> 8, col4 = (q & 255) * 4;
    float4 v = {0.0f, 0.0f, 0.0f, 0.0f};
    if (row < 81) v = *(const float4*)&Wc[row * 1024 + col4];
    else if (row < 401) v = *(const float4*)&Wr[(row - 81) * 1024 + col4];
    union { bf16_t b[4]; uint2 u; } p;
    p.b[0] = (bf16_t)v.x; p.b[1] = (bf16_t)v.y; p.b[2] = (bf16_t)v.z; p.b[3] = (bf16_t)v.w;
    ((uint2*)Wcb)[q] = p.u;
    if (q < 448) bcat[q] = (q < 81) ? bc[q] : ((q < 401) ? br[q - 81] : 0.0f);
  }
}

// ---------------- ROI align on NHWC bf16; A[n][bin*256 + c]; 16B loads, half-wave/bin ----------------
__global__ __launch_bounds__(256) void roi_align_nhwc(const bf16_t* __restrict__ fb2,
                                                      const bf16_t* __restrict__ fb3,
                                                      const bf16_t* __restrict__ fb4,
                                                      const bf16_t* __restrict__ fb5,
                                                      const float* __restrict__ rois,
                                                      bf16_t* __restrict__ A) {
  const int n = blockIdx.x;
  const int t = threadIdx.x;
  const int b = n >> 9;
  const float4 box = ((const float4*)rois)[n];
  const float w = box.z - box.x, h = box.w - box.y;
  const int lv = (int)floorf(4.0f + log2f(sqrtf(w * h) / 224.0f + 1e-6f));
  bf16_t* Ar = A + (size_t)n * 12544;

  if (lv < 2 || lv > 5) {
    uint4 z = {0, 0, 0, 0};
    for (int j = t; j < 1568; j += 256) ((uint4*)Ar)[j] = z;
    return;
  }

  const bf16_t* F; int H, W; float scale;
  if (lv == 2)      { F = fb2; H = 200; W = 200; scale = 0.25f; }
  else if (lv == 3) { F = fb3; H = 100; W = 100; scale = 0.125f; }
  else if (lv == 4) { F = fb4; H = 50;  W = 50;  scale = 0.0625f; }
  else              { F = fb5; H = 25;  W = 25;  scale = 0.03125f; }
  F += (size_t)b * H * W * 256;

  __shared__ int   s_x0[14], s_xb[14], s_y0w[14], s_ybw[14];
  __shared__ float s_wx0[14], s_wx1[14], s_wy0[14], s_wy1[14];

  const float x1s = box.x * scale, y1s = box.y * scale;
  const float x2s = box.z * scale, y2s = box.w * scale;
  const float rw = fmaxf(x2s - x1s, 1.0f), rh = fmaxf(y2s - y1s, 1.0f);
  const float bwx = rw * (1.0f / 7.0f), bwy = rh * (1.0f / 7.0f);

  if (t < 14) {
    const int i2 = t >> 1, j = t & 1;
    const float off = (float)i2 + ((float)j + 0.5f) * 0.5f;
    float x = x1s + off * bwx;
    float vx = (x > -1.0f && x < (float)W) ? 1.0f : 0.0f;
    x = fminf(fmaxf(x, 0.0f), (float)(W - 1));
    float x0f = floorf(x);
    int x0 = (int)x0f;
    s_x0[t] = x0; s_xb[t] = min(x0 + 1, W - 1);
    float lx = x - x0f;
    s_wx0[t] = (1.0f - lx) * vx; s_wx1[t] = lx * vx;
    float y = y1s + off * bwy;
    float vy = (y > -1.0f && y < (float)H) ? 1.0f : 0.0f;
    y = fminf(fmaxf(y, 0.0f), (float)(H - 1));
    float y0f = floorf(y);
    int y0 = (int)y0f;
    s_y0w[t] = y0 * W; s_ybw[t] = min(y0 + 1, H - 1) * W;
    float ly = y - y0f;
    s_wy0[t] = (1.0f - ly) * vy; s_wy1[t] = ly * vy;
  }
  __syncthreads();

  const int wv = t >> 6, l = t & 63;
  const int half = l >> 5, c8 = (l & 31) * 8;
  for (int p = wv; p < 25; p += 4) {
    const int bin = 2 * p + half;
    if (bin >= 49) continue;
    const int by = bin / 7, bx = bin - by * 7;
    float a[8] = {};
#pragma unroll
    for (int sa = 0; sa < 2; sa++) {
      const int my = 2 * by + sa;
      const int y0w = s_y0w[my], ybw = s_ybw[my];
      const float wy0 = s_wy0[my], wy1 = s_wy1[my];
#pragma unroll
      for (int sb = 0; sb < 2; sb++) {
        const int mx = 2 * bx + sb;
        const int x0 = s_x0[mx], xb = s_xb[mx];
        const float w00 = wy0 * s_wx0[mx], w01 = wy0 * s_wx1[mx];
        const float w10 = wy1 * s_wx0[mx], w11 = wy1 * s_wx1[mx];
        bf16x8 v00 = *(const bf16x8*)&F[(size_t)(y0w + x0) * 256 + c8];
        bf16x8 v01 = *(const bf16x8*)&F[(size_t)(y0w + xb) * 256 + c8];
        bf16x8 v10 = *(const bf16x8*)&F[(size_t)(ybw + x0) * 256 + c8];
        bf16x8 v11 = *(const bf16x8*)&F[(size_t)(ybw + xb) * 256 + c8];
#pragma unroll
        for (int k2 = 0; k2 < 8; k2++)
          a[k2] += w00 * (float)v00[k2] + w01 * (float)v01[k2]
                 + w10 * (float)v10[k2] + w11 * (float)v11[k2];
      }
    }
    union { bf16_t bb[8]; uint4 u; } pk;
#pragma unroll
    for (int k2 = 0; k2 < 8; k2++) pk.bb[k2] = (bf16_t)(a[k2] * 0.25f);
    *(uint4*)&Ar[bin * 256 + c8] = pk.u;
  }
}

// ------- fc1: 64x128 tile, GLDS w/ swizzle, split-K=8, fp32 partials -------
// 1-D grid, XCD-grouped: all 16 M-tiles of one (N-tile,K-slice) share bid%8 -> same XCD,
// so the 392KB B-slab is L2-resident and read once per XCD.
__global__ __launch_bounds__(256, 4) void gemm1_splitk(const bf16_t* __restrict__ A,
                                                       const bf16_t* __restrict__ B,
                                                       float* __restrict__ Cp) {
  __shared__ __align__(16) bf16_t As[64 * 32];
  __shared__ __align__(16) bf16_t Bs[128 * 32];
  const int t = threadIdx.x;
  const int bid = blockIdx.x;
  const int x = (bid >> 3) & 15;
  const int yzi = (bid & 7) + 8 * (bid >> 7);
  const int y = yzi >> 3, z = yzi & 7;
  const int w = t >> 6, l = t & 63;
  const int bm = x * 64, bn = y * 128;
  const int K = 12544;
  const int k0 = z * 1568;
  const int row = t >> 2;
  const int kc = ((t & 3) ^ ((t >> 3) & 3)) * 8;   // swizzled source chunk
  const bf16_t* gA  = A + (size_t)(bm + row) * K + k0 + kc;
  const bf16_t* gB1 = B + (size_t)(bn + row) * K + k0 + kc;
  const bf16_t* gB2 = gB1 + (size_t)64 * K;
  bf16_t* lA  = As + w * 512;
  bf16_t* lB1 = Bs + w * 512;
  bf16_t* lB2 = Bs + 2048 + w * 512;
  const int wm = (w & 1) * 32, wn = (w >> 1) * 64;
  const int rA = l & 15;
  const int kqs = (((l >> 4) ^ ((rA >> 1) & 3))) * 8;  // swizzled read chunk
  f32x4 acc[2][4] = {};

  for (int kk = 0; kk < 49; ++kk) {
    GLDS16(gA, lA); GLDS16(gB1, lB1); GLDS16(gB2, lB2);
    gA += 32; gB1 += 32; gB2 += 32;
    __syncthreads();
    bf16x8 a[2], b[4];
#pragma unroll
    for (int i = 0; i < 2; i++) a[i] = *(const bf16x8*)&As[(wm + i * 16 + rA) * 32 + kqs];
#pragma unroll
    for (int j = 0; j < 4; j++) b[j] = *(const bf16x8*)&Bs[(wn + j * 16 + rA) * 32 + kqs];
#pragma unroll
    for (int i = 0; i < 2; i++)
#pragma unroll
      for (int j = 0; j < 4; j++)
        acc[i][j] = __builtin_amdgcn_mfma_f32_16x16x32_bf16(a[i], b[j], acc[i][j], 0, 0, 0);
    __syncthreads();
  }

  const int q = l >> 4, cc = l & 15;
  float* Co = Cp + ((size_t)z << 20);
#pragma unroll
  for (int i = 0; i < 2; i++)
#pragma unroll
    for (int j = 0; j < 4; j++) {
      const int col = bn + wn + j * 16 + cc;
      const int r0 = bm + wm + i * 16 + q * 4;
#pragma unroll
      for (int r = 0; r < 4; r++)
        Co[(size_t)(r0 + r) * 1024 + col] = acc[i][j][r];
    }
}

// ------- split-K reduce + bias + relu + bf16 (1M outputs, 262144 float4 tasks) -------
__global__ __launch_bounds__(256) void reduce_fc1(const float* __restrict__ Cp,
                                                  const float* __restrict__ bias,
                                                  bf16_t* __restrict__ X) {
  const int i4 = blockIdx.x * 256 + threadIdx.x;
  const float4* C4 = (const float4*)Cp;
  float4 s = C4[i4];
#pragma unroll
  for (int z = 1; z < 8; z++) {
    float4 v = C4[(size_t)z * 262144 + i4];
    s.x += v.x; s.y += v.y; s.z += v.z; s.w += v.w;
  }
  const float4 bv = *(const float4*)&bias[(i4 & 255) * 4];
  union { bf16_t bb[4]; uint2 u; } pk;
  pk.bb[0] = (bf16_t)fmaxf(s.x + bv.x, 0.0f);
  pk.bb[1] = (bf16_t)fmaxf(s.y + bv.y, 0.0f);
  pk.bb[2] = (bf16_t)fmaxf(s.z + bv.z, 0.0f);
  pk.bb[3] = (bf16_t)fmaxf(s.w + bv.w, 0.0f);
  ((uint2*)X)[i4] = pk.u;
}

// ---------------- GEMM (64x64 tile, swizzled LDS): C = epi(A x B^T + bias) ----------------
template <int MODE>
__global__ __launch_bounds__(256) void gemm_bt(const bf16_t* __restrict__ A,
                                               const bf16_t* __restrict__ B,
                                               const float* __restrict__ bias,
                                               void* __restrict__ out,
                                               int M, int N, int K) {
  __shared__ __align__(16) bf16_t As[64 * 32];
  __shared__ __align__(16) bf16_t Bs[64 * 32];
  const int t = threadIdx.x;
  const int wv = t >> 6, l = t & 63;
  const int bm = blockIdx.x * 64, bn = blockIdx.y * 64;
  const int wm = (wv >> 1) * 32, wn = (wv & 1) * 32;

  const int srow = t >> 2;
  const int skc = (t & 3) * 8;
  const int sst = ((t & 3) ^ ((t >> 3) & 3)) * 8;
  const bf16_t* ga = A + (size_t)(bm + srow) * K + skc;
  const bf16_t* gb = B + (size_t)(bn + srow) * K + skc;

  uint4 ra = *(const uint4*)ga;
  uint4 rb = *(const uint4*)gb;
  f32x4 acc[2][2] = {};

  const int nIter = K >> 5;
  const int rA = l & 15;
  const int kqs = (((l >> 4) ^ ((rA >> 1) & 3))) * 8;
  for (int i = 0; i < nIter; ++i) {
    ga += 32; gb += 32;
    *(uint4*)&As[srow * 32 + sst] = ra;
    *(uint4*)&Bs[srow * 32 + sst] = rb;
    __syncthreads();
    if (i + 1 < nIter) { ra = *(const uint4*)ga; rb = *(const uint4*)gb; }
    bf16x8 a0 = *(const bf16x8*)&As[(wm + rA) * 32 + kqs];
    bf16x8 a1 = *(const bf16x8*)&As[(wm + 16 + rA) * 32 + kqs];
    bf16x8 b0 = *(const bf16x8*)&Bs[(wn + rA) * 32 + kqs];
    bf16x8 b1 = *(const bf16x8*)&Bs[(wn + 16 + rA) * 32 + kqs];
    acc[0][0] = __builtin_amdgcn_mfma_f32_16x16x32_bf16(a0, b0, acc[0][0], 0, 0, 0);
    acc[0][1] = __builtin_amdgcn_mfma_f32_16x16x32_bf16(a0, b1, acc[0][1], 0, 0, 0);
    acc[1][0] = __builtin_amdgcn_mfma_f32_16x16x32_bf16(a1, b0, acc[1][0], 0, 0, 0);
    acc[1][1] = __builtin_amdgcn_mfma_f32_16x16x32_bf16(a1, b1, acc[1][1], 0, 0, 0);
    __syncthreads();
  }

  const int q = l >> 4;
  const int cc = l & 15;
#pragma unroll
  for (int i2 = 0; i2 < 2; i2++) {
#pragma unroll
    for (int j2 = 0; j2 < 2; j2++) {
      const int col = bn + wn + j2 * 16 + cc;
      const int row0 = bm + wm + i2 * 16 + q * 4;
      const float bv = bias[col];
#pragma unroll
      for (int r = 0; r < 4; r++) {
        float v = acc[i2][j2][r] + bv;
        const int row = row0 + r;
        if (MODE == 0) {
          v = fmaxf(v, 0.0f);
          ((bf16_t*)out)[(size_t)row * N + col] = (bf16_t)v;
        } else {
          if (col < 81)       ((float*)out)[(size_t)row * 81 + col] = v;
          else if (col < 401) ((float*)out)[82944 + (size_t)row * 320 + (col - 81)] = v;
        }
      }
    }
  }
}

extern "C" void kernel_launch(void* const* d_in, const int* in_sizes, int n_in,
                              void* d_out, int out_size, void* d_ws, size_t ws_size,
                              hipStream_t stream) {
  const float* f2   = (const float*)d_in[0];
  const float* f3   = (const float*)d_in[1];
  const float* f4   = (const float*)d_in[2];
  const float* f5   = (const float*)d_in[3];
  const float* rois = (const float*)d_in[4];
  const float* W1   = (const float*)d_in[5];
  const float* b1   = (const float*)d_in[6];
  const float* W2   = (const float*)d_in[7];
  const float* b2   = (const float*)d_in[8];
  const float* Wc   = (const float*)d_in[9];
  const float* bc   = (const float*)d_in[10];
  const float* Wr   = (const float*)d_in[11];
  const float* br   = (const float*)d_in[12];

  char* ws = (char*)d_ws;
  bf16_t* Ab   = (bf16_t*)(ws);                 // 1024x12544 bf16
  bf16_t* W1b  = (bf16_t*)(ws + 25690112);      // 1024x12544 bf16 (K-permuted)
  bf16_t* X1b  = (bf16_t*)(ws + 51380224);      // 1024x1024 bf16
  bf16_t* W2b  = (bf16_t*)(ws + 53477376);      // 1024x1024 bf16
  bf16_t* X2b  = (bf16_t*)(ws + 55574528);      // 1024x1024 bf16
  bf16_t* Wcb  = (bf16_t*)(ws + 57671680);      // 448x1024 bf16
  float*  bcat = (float*)(ws + 58589184);       // 448 fp32
  bf16_t* FT   = (bf16_t*)(ws + 58591232);      // NHWC feats bf16 (54.4 MB)
  float*  Cp   = (float*)(ws + 58591232);       // fc1 split-K partials (aliases FT)
  bf16_t* FT2 = FT;
  bf16_t* FT3 = FT + 20480000;
  bf16_t* FT4 = FT + 25600000;
  bf16_t* FT5 = FT + 26880000;

  prep_all<<<5200, 256, 0, stream>>>(f2, f3, f4, f5, W1, W2, Wc, bc, Wr, br,
                                     FT2, FT3, FT4, FT5, W1b, W2b, Wcb, bcat);
  roi_align_nhwc<<<1024, 256, 0, stream>>>(FT2, FT3, FT4, FT5, rois, Ab);
  gemm1_splitk<<<1024, 256, 0, stream>>>(Ab, W1b, Cp);
  reduce_fc1<<<1024, 256, 0, stream>>>(Cp, b1, X1b);
  gemm_bt<0><<<dim3(16, 16), 256, 0, stream>>>(X1b, W2b, b2, (void*)X2b, 1024, 1024, 1024);
  gemm_bt<1><<<dim3(16, 7), 256, 0, stream>>>(X2b, Wcb, bcat, d_out, 1024, 448, 1024);
}